// Round 6
// baseline (899.330 us; speedup 1.0000x reference)
//
#include <hip/hip_runtime.h>
#include <math.h>

#define GRIDN    128
#define NRAYS    16384
#define STEPSZ   0.5f
#define MAXSTEPS 320
#define NVOX     (GRIDN * GRIDN * GRIDN)
// fp16 record: 32 halves (64 B) per VOXEL: [0]=density, [1..27]=sh, pad.
// Voxel-indexed (links folded in at repack time); empty voxels = zero record.
#define PACK_BYTES ((size_t)(NVOX + 1) * 64)
// fp16 voxel-density array (4.2 MB, L2-resident): drives sigma cheaply.
#define DENS_BYTES ((size_t)NVOX * 2)

// ---- tile/segment decomposition for the march ----
#define TILES  256                  // 16x16 tiles of 8x8 pixels
#define WPB    4                    // waves per block

static inline size_t part_bytes(int nseg) {
    return (size_t)nseg * TILES * 64 * 8 * 4;
}

typedef _Float16 half8 __attribute__((ext_vector_type(8)));

// ---------------------------------------------------------------------------
// Prologue: voxel-indexed repack (round-5 structure) + fp16 density array.
// ---------------------------------------------------------------------------
__global__ __launch_bounds__(256, 8)
void repack_kernel(const int*   __restrict__ links,
                   const float* __restrict__ density,
                   const float* __restrict__ sh,
                   _Float16*    __restrict__ pack,
                   _Float16*    __restrict__ dens16)
{
    __shared__ _Float16 rec[256 * 32];   // 16 KB: 256 records
    const int tid   = threadIdx.x;
    const int vbase = blockIdx.x * 256;

    // Phase 1: vectorized coalesced read of the block's 256 sh rows
    // (1728 float4), fp16-convert, scatter into record layout in LDS.
    const float4* src4 = (const float4*)(sh + (size_t)vbase * 27);
    #pragma unroll
    for (int it = 0; it < 7; it++) {
        const int idx = it * 256 + tid;          // float4 index within block
        if (idx < 1728) {
            const float4 v = src4[idx];
            const int n0 = idx * 4;
            const float vv[4] = { v.x, v.y, v.z, v.w };
            #pragma unroll
            for (int e = 0; e < 4; e++) {
                const int n   = n0 + e;
                const int row = n / 27;          // compiler magic-mul
                const int k   = n - row * 27;
                rec[row * 32 + 1 + k] = (_Float16)vv[e];
            }
        }
    }

    const int lnk  = links[vbase + tid];
    const float dens = (lnk >= 0) ? density[lnk] : 0.0f;
    dens16[vbase + tid] = (_Float16)dens;        // coalesced fp16 density array

    __syncthreads();

    // General-links fixup: if lnk != own row, capture correct data first.
    const bool fix = (lnk >= 0) && (lnk != vbase + tid);
    float tmp[27];
    if (fix) {
        if (lnk >= vbase && lnk < vbase + 256) {
            const _Float16* s = rec + (lnk - vbase) * 32 + 1;
            #pragma unroll
            for (int k = 0; k < 27; k++) tmp[k] = (float)s[k];
        } else {
            const float* row = sh + (size_t)lnk * 27;
            #pragma unroll
            for (int k = 0; k < 27; k++) tmp[k] = row[k];
        }
    }
    __syncthreads();

    _Float16* my = rec + tid * 32;
    my[0]  = (_Float16)dens;
    my[28] = (_Float16)0.0f; my[29] = (_Float16)0.0f;
    my[30] = (_Float16)0.0f; my[31] = (_Float16)0.0f;
    if (lnk < 0) {
        #pragma unroll
        for (int k = 0; k < 27; k++) my[1 + k] = (_Float16)0.0f;
    } else if (fix) {
        #pragma unroll
        for (int k = 0; k < 27; k++) my[1 + k] = (_Float16)tmp[k];
    }
    __syncthreads();

    // Phase 3: fully coalesced LDS->global copy (16 KB / block).
    const uint4* ls = (const uint4*)rec;
    uint4* gd = (uint4*)(pack + (size_t)vbase * 32);
    #pragma unroll
    for (int i = 0; i < 4; i++)
        gd[i * 256 + tid] = ls[i * 256 + tid];
}

// ---------------------------------------------------------------------------
// March partials: round-3 proven structure + LAZY SH fetch.
// sigma comes from the 4.2 MB L2-resident dens16 array (8 x 2B gathers per
// cell-change). The 8 x 64B SH records are fetched only when a lane actually
// has sigma > 0 in a cell (weight is exactly 0 otherwise -> skipped math
// contributes exactly 0; bit-identical result). Masked lanes generate no
// memory traffic, cutting the TA line-processing that bounds this kernel.
// NOTE: full-8-corner unrolled reloads only (round-4 lesson: partial array
// updates under branchy CFG spill to scratch).
// ---------------------------------------------------------------------------
template <int NSEG>
__global__ __launch_bounds__(256, 8)
void march_part_kernel(const float* __restrict__ origins,
                       const float* __restrict__ dirs,
                       const _Float16* __restrict__ pack,
                       const _Float16* __restrict__ dens16,
                       float* __restrict__ parts)
{
    constexpr int SPSEG = MAXSTEPS / NSEG;
    const int lane = threadIdx.x & 63;
    const int gw   = blockIdx.x * WPB + (threadIdx.x >> 6);
    const int seg  = gw >> 8;              // seg-major dispatch
    const int tile = gw & (TILES - 1);
    const int ray  = (((tile >> 4) * 8 + (lane >> 3)) << 7)
                   + ((tile & 15) << 3) + (lane & 7);

    // ---- ray setup ----
    const float owx = origins[ray * 3 + 0];
    const float owy = origins[ray * 3 + 1];
    const float owz = origins[ray * 3 + 2];
    const float dwx = dirs[ray * 3 + 0];
    const float dwy = dirs[ray * 3 + 1];
    const float dwz = dirs[ray * 3 + 2];

    const float invn = 1.0f / sqrtf(dwx * dwx + dwy * dwy + dwz * dwz);
    const float vx = dwx * invn, vy = dwy * invn, vz = dwz * invn;

    const float ox = 63.5f + owx * 64.0f;
    const float oy = 63.5f + owy * 64.0f;
    const float oz = 63.5f + owz * 64.0f;

    const float sxx = vx * 64.0f, syy = vy * 64.0f, szz = vz * 64.0f;
    const float ds  = 1.0f / sqrtf(sxx * sxx + syy * syy + szz * szz);
    const float dx = sxx * ds, dy = syy * ds, dz = szz * ds;

    float shm[9];
    shm[0] = 0.28209479177387814f;
    shm[1] = -0.4886025119029199f * vy;
    shm[2] =  0.4886025119029199f * vz;
    shm[3] = -0.4886025119029199f * vx;
    shm[4] =  1.0925484305920792f * vx * vy;
    shm[5] = -1.0925484305920792f * vy * vz;
    shm[6] =  0.31539156525252005f * (2.0f * vz * vz - vx * vx - vy * vy);
    shm[7] = -1.0925484305920792f * vx * vz;
    shm[8] =  0.5462742152960396f * (vx * vx - vy * vy);

    float t0 = 0.0f, tmax = 1e9f;
    {
        const float o3[3] = { ox, oy, oz };
        const float d3[3] = { dx, dy, dz };
        #pragma unroll
        for (int a = 0; a < 3; a++) {
            if (d3[a] != 0.0f) {
                float inv = 1.0f / d3[a];
                float ta = (-0.5f  - o3[a]) * inv;
                float tb = (127.5f - o3[a]) * inv;
                t0   = fmaxf(t0,   fminf(ta, tb));
                tmax = fminf(tmax, fmaxf(ta, tb));
            }
        }
    }

    float ll = 0.0f;
    float light = 1.0f;
    float aR = 0, aG = 0, aB = 0, aA = 0, aD1 = 0, aD2 = 0;

    int cached_cell = -1;    // density-cache cell
    int sh_cell     = -1;    // SH-projection-cache cell (lazy)
    float csig[8], cr0[8], cr1[8], cr2[8];

    const int k0 = seg * SPSEG;
    for (int i = 0; i < SPSEG; i++) {
        const float t = t0 + (float)(k0 + i) * STEPSZ;
        if (t > tmax) break;

        float px = fminf(fmaxf(ox + t * dx, 0.0f), 127.0f);
        float py = fminf(fmaxf(oy + t * dy, 0.0f), 127.0f);
        float pz = fminf(fmaxf(oz + t * dz, 0.0f), 127.0f);
        const int lx = min(max((int)px, 0), 126);
        const int ly = min(max((int)py, 0), 126);
        const int lz = min(max((int)pz, 0), 126);
        const float fx = px - (float)lx;
        const float fy = py - (float)ly;
        const float fz = pz - (float)lz;

        const int cell = (lx << 14) | (ly << 7) | lz;
        if (cell != cached_cell) {
            cached_cell = cell;
            #pragma unroll
            for (int c = 0; c < 8; c++) {
                const int off = (((c >> 2) & 1) << 14) + (((c >> 1) & 1) << 7) + (c & 1);
                csig[c] = (float)dens16[cell + off];
            }
        }

        const float gx1 = fx, gx0 = 1.0f - fx;
        const float gy1 = fy, gy0 = 1.0f - fy;
        const float gz1 = fz, gz0 = 1.0f - fz;
        float w[8];
        w[0] = gx0*gy0*gz0; w[1] = gx0*gy0*gz1; w[2] = gx0*gy1*gz0; w[3] = gx0*gy1*gz1;
        w[4] = gx1*gy0*gz0; w[5] = gx1*gy0*gz1; w[6] = gx1*gy1*gz0; w[7] = gx1*gy1*gz1;

        float sigma = 0;
        #pragma unroll
        for (int c = 0; c < 8; c++) sigma += w[c] * csig[c];

        const float la = -STEPSZ * fmaxf(sigma, 0.0f) * ds;
        const float e  = __expf(la);
        const float ws = light * (1.0f - e);

        if (sigma > 0.0f) {          // ws == 0 exactly otherwise
            if (cell != sh_cell) {
                sh_cell = cell;
                #pragma unroll
                for (int c = 0; c < 8; c++) {
                    const int off = (((c >> 2) & 1) << 14) + (((c >> 1) & 1) << 7) + (c & 1);
                    const half8* pr = (const half8*)(pack + (size_t)(cell + off) * 32);
                    const half8 h0 = pr[0], h1 = pr[1], h2 = pr[2], h3 = pr[3];
                    cr0[c] = shm[0]*(float)h0[1] + shm[1]*(float)h0[2] + shm[2]*(float)h0[3]
                           + shm[3]*(float)h0[4] + shm[4]*(float)h0[5] + shm[5]*(float)h0[6]
                           + shm[6]*(float)h0[7] + shm[7]*(float)h1[0] + shm[8]*(float)h1[1];
                    cr1[c] = shm[0]*(float)h1[2] + shm[1]*(float)h1[3] + shm[2]*(float)h1[4]
                           + shm[3]*(float)h1[5] + shm[4]*(float)h1[6] + shm[5]*(float)h1[7]
                           + shm[6]*(float)h2[0] + shm[7]*(float)h2[1] + shm[8]*(float)h2[2];
                    cr2[c] = shm[0]*(float)h2[3] + shm[1]*(float)h2[4] + shm[2]*(float)h2[5]
                           + shm[3]*(float)h2[6] + shm[4]*(float)h2[7] + shm[5]*(float)h3[0]
                           + shm[6]*(float)h3[1] + shm[7]*(float)h3[2] + shm[8]*(float)h3[3];
                }
            }
            float c0 = 0, c1 = 0, c2 = 0;
            #pragma unroll
            for (int c = 0; c < 8; c++) {
                c0 += w[c] * cr0[c];
                c1 += w[c] * cr1[c];
                c2 += w[c] * cr2[c];
            }
            c0 = fmaxf(c0 + 0.5f, 0.0f);
            c1 = fmaxf(c1 + 0.5f, 0.0f);
            c2 = fmaxf(c2 + 0.5f, 0.0f);
            aR += ws * c0; aG += ws * c1; aB += ws * c2;
        }

        aA += ws;
        const float dd = t * ds;
        aD1 += ws * dd;
        aD2 += ws * dd * dd;
        light *= e;
        ll    += la;
    }

    // SoA partials: two float4 arrays, coalesced stores.
    const size_t pidx = (size_t)(seg * TILES + tile) * 64 + lane;
    float4* pa = (float4*)parts;
    float4* pb = pa + (size_t)NSEG * TILES * 64;
    pa[pidx] = make_float4(aR, aG, aB, aA);
    pb[pidx] = make_float4(aD1, aD2, ll, 0.0f);
}

// ---------------------------------------------------------------------------
// Stitch: one thread per ray combines its NSEG partials.
// ---------------------------------------------------------------------------
template <int NSEG>
__global__ __launch_bounds__(256)
void stitch_kernel(const float* __restrict__ parts, float* __restrict__ out)
{
    const int idx  = blockIdx.x * 256 + threadIdx.x;   // (tile, lane) id
    const int tile = idx >> 6;
    const int lane = idx & 63;
    const int ray  = (((tile >> 4) * 8 + (lane >> 3)) << 7)
                   + ((tile & 15) << 3) + (lane & 7);

    const float4* pa = (const float4*)parts;
    const float4* pb = pa + (size_t)NSEG * TILES * 64;

    float pre = 0.0f;
    float R = 0, G = 0, B = 0, A = 0, D1 = 0, D2 = 0;
    #pragma unroll 4
    for (int s = 0; s < NSEG; s++) {
        const size_t pidx = (size_t)(s * TILES + tile) * 64 + lane;
        const float4 a = pa[pidx];
        const float4 b = pb[pidx];
        const float T = __expf(pre);
        R  += T * a.x;  G  += T * a.y;  B  += T * a.z;  A += T * a.w;
        D1 += T * b.x;  D2 += T * b.y;
        pre += b.z;
    }

    const float bg    = __expf(pre);
    const float denom = fmaxf(A, 1e-10f);
    const float E     = D1 / denom;
    const float ov    = D2 - 2.0f * E * D1 + E * E * A;

    const int o = ray * 6;
    out[o + 0] = R + bg;
    out[o + 1] = G + bg;
    out[o + 2] = B + bg;
    out[o + 3] = A;
    out[o + 4] = E;
    out[o + 5] = ov / denom;
}

// ---------------------------------------------------------------------------
// Fallback (no workspace): verified round-1 math, direct links/density/sh
// reads, wave = 1 ray with shfl stitch.
// ---------------------------------------------------------------------------
__global__ __launch_bounds__(256, 8)
void march_fallback_kernel(const float* __restrict__ origins,
                           const float* __restrict__ dirs,
                           const int*   __restrict__ links,
                           const float* __restrict__ density,
                           const float* __restrict__ sh,
                           float* __restrict__ out)
{
    const int tid  = threadIdx.x;
    const int lane = tid & 63;
    const int r    = tid >> 6;
    const int ray  = blockIdx.x * 4 + r;

    const float owx = origins[ray * 3 + 0];
    const float owy = origins[ray * 3 + 1];
    const float owz = origins[ray * 3 + 2];
    const float dwx = dirs[ray * 3 + 0];
    const float dwy = dirs[ray * 3 + 1];
    const float dwz = dirs[ray * 3 + 2];

    const float invn = 1.0f / sqrtf(dwx * dwx + dwy * dwy + dwz * dwz);
    const float vx = dwx * invn, vy = dwy * invn, vz = dwz * invn;
    const float ox = 63.5f + owx * 64.0f;
    const float oy = 63.5f + owy * 64.0f;
    const float oz = 63.5f + owz * 64.0f;
    const float sxx = vx * 64.0f, syy = vy * 64.0f, szz = vz * 64.0f;
    const float ds  = 1.0f / sqrtf(sxx * sxx + syy * syy + szz * szz);
    const float dx = sxx * ds, dy = syy * ds, dz = szz * ds;

    float shm[9];
    shm[0] = 0.28209479177387814f;
    shm[1] = -0.4886025119029199f * vy;
    shm[2] =  0.4886025119029199f * vz;
    shm[3] = -0.4886025119029199f * vx;
    shm[4] =  1.0925484305920792f * vx * vy;
    shm[5] = -1.0925484305920792f * vy * vz;
    shm[6] =  0.31539156525252005f * (2.0f * vz * vz - vx * vx - vy * vy);
    shm[7] = -1.0925484305920792f * vx * vz;
    shm[8] =  0.5462742152960396f * (vx * vx - vy * vy);

    float t0 = 0.0f, tmax = 1e9f;
    {
        const float o3[3] = { ox, oy, oz };
        const float d3[3] = { dx, dy, dz };
        #pragma unroll
        for (int a = 0; a < 3; a++) {
            if (d3[a] != 0.0f) {
                float inv = 1.0f / d3[a];
                float ta = (-0.5f  - o3[a]) * inv;
                float tb = (127.5f - o3[a]) * inv;
                t0   = fmaxf(t0,   fminf(ta, tb));
                tmax = fminf(tmax, fmaxf(ta, tb));
            }
        }
    }

    float ll = 0.0f, light = 1.0f;
    float aR = 0, aG = 0, aB = 0, aA = 0, aD1 = 0, aD2 = 0;
    int cached_cell = -1;
    float csig[8], cr0[8], cr1[8], cr2[8];

    const int k0 = lane * (MAXSTEPS / 64);
    for (int i = 0; i < MAXSTEPS / 64; i++) {
        const float t = t0 + (float)(k0 + i) * STEPSZ;
        if (t > tmax) break;

        float px = fminf(fmaxf(ox + t * dx, 0.0f), 127.0f);
        float py = fminf(fmaxf(oy + t * dy, 0.0f), 127.0f);
        float pz = fminf(fmaxf(oz + t * dz, 0.0f), 127.0f);
        const int lx = min(max((int)px, 0), 126);
        const int ly = min(max((int)py, 0), 126);
        const int lz = min(max((int)pz, 0), 126);
        const float fx = px - (float)lx;
        const float fy = py - (float)ly;
        const float fz = pz - (float)lz;

        const int cell = (lx << 14) | (ly << 7) | lz;
        if (cell != cached_cell) {
            cached_cell = cell;
            #pragma unroll
            for (int c = 0; c < 8; c++) {
                const int cdx = (c >> 2) & 1, cdy = (c >> 1) & 1, cdz = c & 1;
                const int idx = cell + (cdx << 14) + (cdy << 7) + cdz;
                const int lnk = links[idx];
                float sg = 0, q0 = 0, q1 = 0, q2 = 0;
                if (lnk >= 0) {
                    sg = density[lnk];
                    const float* row = sh + (size_t)lnk * 27;
                    #pragma unroll
                    for (int k = 0; k < 9; k++) {
                        const float m = shm[k];
                        q0 += m * row[k];
                        q1 += m * row[9 + k];
                        q2 += m * row[18 + k];
                    }
                }
                csig[c] = sg; cr0[c] = q0; cr1[c] = q1; cr2[c] = q2;
            }
        }

        const float gx1 = fx, gx0 = 1.0f - fx;
        const float gy1 = fy, gy0 = 1.0f - fy;
        const float gz1 = fz, gz0 = 1.0f - fz;
        float w[8];
        w[0] = gx0*gy0*gz0; w[1] = gx0*gy0*gz1; w[2] = gx0*gy1*gz0; w[3] = gx0*gy1*gz1;
        w[4] = gx1*gy0*gz0; w[5] = gx1*gy0*gz1; w[6] = gx1*gy1*gz0; w[7] = gx1*gy1*gz1;

        float sigma = 0, c0 = 0, c1 = 0, c2 = 0;
        #pragma unroll
        for (int c = 0; c < 8; c++) {
            sigma += w[c] * csig[c];
            c0    += w[c] * cr0[c];
            c1    += w[c] * cr1[c];
            c2    += w[c] * cr2[c];
        }

        const float la = -STEPSZ * fmaxf(sigma, 0.0f) * ds;
        const float e  = __expf(la);
        const float ws = light * (1.0f - e);
        c0 = fmaxf(c0 + 0.5f, 0.0f);
        c1 = fmaxf(c1 + 0.5f, 0.0f);
        c2 = fmaxf(c2 + 0.5f, 0.0f);

        aR += ws * c0; aG += ws * c1; aB += ws * c2;
        aA += ws;
        const float dd = t * ds;
        aD1 += ws * dd;
        aD2 += ws * dd * dd;
        light *= e;
        ll    += la;
    }

    float inc = ll;
    #pragma unroll
    for (int off = 1; off < 64; off <<= 1) {
        const float v = __shfl_up(inc, off, 64);
        if (lane >= off) inc += v;
    }
    const float pre = inc - ll;
    const float T   = __expf(pre);
    aR *= T; aG *= T; aB *= T; aA *= T; aD1 *= T; aD2 *= T;

    #pragma unroll
    for (int off = 32; off; off >>= 1) {
        aR  += __shfl_xor(aR,  off, 64);
        aG  += __shfl_xor(aG,  off, 64);
        aB  += __shfl_xor(aB,  off, 64);
        aA  += __shfl_xor(aA,  off, 64);
        aD1 += __shfl_xor(aD1, off, 64);
        aD2 += __shfl_xor(aD2, off, 64);
    }
    const float llt = __shfl(inc, 63, 64);

    if (lane == 0) {
        const float bg    = __expf(llt);
        const float denom = fmaxf(aA, 1e-10f);
        const float E     = aD1 / denom;
        const float ov    = aD2 - 2.0f * E * aD1 + E * E * aA;
        const int o = ray * 6;
        out[o + 0] = aR + bg;
        out[o + 1] = aG + bg;
        out[o + 2] = aB + bg;
        out[o + 3] = aA;
        out[o + 4] = E;
        out[o + 5] = ov / denom;
    }
}

extern "C" void kernel_launch(void* const* d_in, const int* in_sizes, int n_in,
                              void* d_out, int out_size, void* d_ws, size_t ws_size,
                              hipStream_t stream) {
    const float* origins = (const float*)d_in[0];
    const float* dirs    = (const float*)d_in[1];
    const int*   links   = (const int*)d_in[2];
    const float* density = (const float*)d_in[3];
    const float* sh      = (const float*)d_in[4];
    float* out = (float*)d_out;

    if (ws_size >= PACK_BYTES + part_bytes(32) + DENS_BYTES) {
        _Float16* pack   = (_Float16*)d_ws;
        float*    parts  = (float*)((char*)d_ws + PACK_BYTES);
        _Float16* dens16 = (_Float16*)((char*)d_ws + PACK_BYTES + part_bytes(32));
        // DIAGNOSTIC (this round): repack launched TWICE (idempotent).
        // Delta in (total - march) vs round 5 == one repack's true duration,
        // separating repack cost from the invariant ~330 us residual.
        repack_kernel<<<dim3(NVOX / 256), dim3(256), 0, stream>>>(links, density, sh, pack, dens16);
        repack_kernel<<<dim3(NVOX / 256), dim3(256), 0, stream>>>(links, density, sh, pack, dens16);
        march_part_kernel<32><<<dim3(TILES * 32 / WPB), dim3(256), 0, stream>>>(
            origins, dirs, pack, dens16, parts);
        stitch_kernel<32><<<dim3(NRAYS / 256), dim3(256), 0, stream>>>(parts, out);
    } else if (ws_size >= PACK_BYTES + part_bytes(16) + DENS_BYTES) {
        _Float16* pack   = (_Float16*)d_ws;
        float*    parts  = (float*)((char*)d_ws + PACK_BYTES);
        _Float16* dens16 = (_Float16*)((char*)d_ws + PACK_BYTES + part_bytes(16));
        repack_kernel<<<dim3(NVOX / 256), dim3(256), 0, stream>>>(links, density, sh, pack, dens16);
        march_part_kernel<16><<<dim3(TILES * 16 / WPB), dim3(256), 0, stream>>>(
            origins, dirs, pack, dens16, parts);
        stitch_kernel<16><<<dim3(NRAYS / 256), dim3(256), 0, stream>>>(parts, out);
    } else {
        march_fallback_kernel<<<dim3(NRAYS / 4), dim3(256), 0, stream>>>(
            origins, dirs, links, density, sh, out);
    }
}

// Round 7
// 653.556 us; speedup vs baseline: 1.3761x; 1.3761x over previous
//
#include <hip/hip_runtime.h>
#include <math.h>

#define GRIDN    128
#define NRAYS    16384
#define STEPSZ   0.5f
#define MAXSTEPS 320
#define SEGS     32
#define SPS      (MAXSTEPS / SEGS)   // 10 steps per segment
#define RPB      8                   // rays per block
#define TPB      (RPB * SEGS)        // 256 threads; wave = 8 rays x 8 segs
#define NVOX     (GRIDN * GRIDN * GRIDN)
// fp16 record: 32 halves (64 B) per VOXEL: [0]=density, [1..27]=sh, pad.
// Voxel-indexed (links folded in at repack time); empty voxels = zero record.
#define PACK_BYTES ((size_t)NVOX * 64)

typedef _Float16 half8 __attribute__((ext_vector_type(8)));

// ---------------------------------------------------------------------------
// Prologue: voxel-indexed repack (round-5 proven: float4 coalesced reads,
// LDS-assembled records, fully-coalesced contiguous stores). ~80 us measured
// (round-6 double-launch diagnostic).
// ---------------------------------------------------------------------------
__global__ __launch_bounds__(256, 8)
void repack_kernel(const int*   __restrict__ links,
                   const float* __restrict__ density,
                   const float* __restrict__ sh,
                   _Float16*    __restrict__ pack)
{
    __shared__ _Float16 rec[256 * 32];   // 16 KB: 256 records
    const int tid   = threadIdx.x;
    const int vbase = blockIdx.x * 256;

    // Phase 1: vectorized coalesced read of the block's 256 sh rows
    // (1728 float4), fp16-convert, scatter into record layout in LDS.
    const float4* src4 = (const float4*)(sh + (size_t)vbase * 27);
    #pragma unroll
    for (int it = 0; it < 7; it++) {
        const int idx = it * 256 + tid;          // float4 index within block
        if (idx < 1728) {
            const float4 v = src4[idx];
            const int n0 = idx * 4;
            const float vv[4] = { v.x, v.y, v.z, v.w };
            #pragma unroll
            for (int e = 0; e < 4; e++) {
                const int n   = n0 + e;
                const int row = n / 27;          // compiler magic-mul
                const int k   = n - row * 27;
                rec[row * 32 + 1 + k] = (_Float16)vv[e];
            }
        }
    }

    const int lnk  = links[vbase + tid];
    const float dens = (lnk >= 0) ? density[lnk] : 0.0f;

    __syncthreads();

    // General-links fixup: if lnk != own row, capture correct data first.
    // (Identity links — the common case — never takes this path.)
    const bool fix = (lnk >= 0) && (lnk != vbase + tid);
    float tmp[27];
    if (fix) {
        if (lnk >= vbase && lnk < vbase + 256) {
            const _Float16* s = rec + (lnk - vbase) * 32 + 1;
            #pragma unroll
            for (int k = 0; k < 27; k++) tmp[k] = (float)s[k];
        } else {
            const float* row = sh + (size_t)lnk * 27;
            #pragma unroll
            for (int k = 0; k < 27; k++) tmp[k] = row[k];
        }
    }
    __syncthreads();

    _Float16* my = rec + tid * 32;
    my[0]  = (_Float16)dens;
    my[28] = (_Float16)0.0f; my[29] = (_Float16)0.0f;
    my[30] = (_Float16)0.0f; my[31] = (_Float16)0.0f;
    if (lnk < 0) {
        #pragma unroll
        for (int k = 0; k < 27; k++) my[1 + k] = (_Float16)0.0f;
    } else if (fix) {
        #pragma unroll
        for (int k = 0; k < 27; k++) my[1 + k] = (_Float16)tmp[k];
    }
    __syncthreads();

    // Phase 3: fully coalesced LDS->global copy (16 KB / block).
    const uint4* ls = (const uint4*)rec;
    uint4* gd = (uint4*)(pack + (size_t)vbase * 32);
    #pragma unroll
    for (int i = 0; i < 4; i++)
        gd[i * 256 + tid] = ls[i * 256 + tid];
}

// ---------------------------------------------------------------------------
// March: ROUND-0 structure verbatim (proven 292 us steady, FETCH 343 MB —
// the best march measured; wave = 8 adjacent rays x 8 consecutive depth
// segments keeps the ray-tube's voxels in L1 across depth), with the one
// proven improvement: voxel-indexed pack (no links gather, one memory
// round-trip per cell-change instead of two).
// Segments stitched in-block via transmittance decomposition (LDS).
// ---------------------------------------------------------------------------
template <bool PACKED>
__global__ __launch_bounds__(TPB, 6)
void march_kernel(const float* __restrict__ origins,
                  const float* __restrict__ dirs,
                  const int*   __restrict__ links,
                  const float* __restrict__ density,
                  const float* __restrict__ sh,
                  const _Float16* __restrict__ pack,
                  float* __restrict__ out)
{
    __shared__ float part[SEGS][RPB][8];

    const int tid = threadIdx.x;
    const int r   = tid & (RPB - 1);
    const int seg = tid / RPB;
    const int ray = blockIdx.x * RPB + r;

    // ---- ray setup ----
    const float owx = origins[ray * 3 + 0];
    const float owy = origins[ray * 3 + 1];
    const float owz = origins[ray * 3 + 2];
    const float dwx = dirs[ray * 3 + 0];
    const float dwy = dirs[ray * 3 + 1];
    const float dwz = dirs[ray * 3 + 2];

    const float invn = 1.0f / sqrtf(dwx * dwx + dwy * dwy + dwz * dwz);
    const float vx = dwx * invn, vy = dwy * invn, vz = dwz * invn;

    const float ox = 63.5f + owx * 64.0f;
    const float oy = 63.5f + owy * 64.0f;
    const float oz = 63.5f + owz * 64.0f;

    const float sxx = vx * 64.0f, syy = vy * 64.0f, szz = vz * 64.0f;
    const float ds  = 1.0f / sqrtf(sxx * sxx + syy * syy + szz * szz);
    const float dx = sxx * ds, dy = syy * ds, dz = szz * ds;

    float shm[9];
    shm[0] = 0.28209479177387814f;
    shm[1] = -0.4886025119029199f * vy;
    shm[2] =  0.4886025119029199f * vz;
    shm[3] = -0.4886025119029199f * vx;
    shm[4] =  1.0925484305920792f * vx * vy;
    shm[5] = -1.0925484305920792f * vy * vz;
    shm[6] =  0.31539156525252005f * (2.0f * vz * vz - vx * vx - vy * vy);
    shm[7] = -1.0925484305920792f * vx * vz;
    shm[8] =  0.5462742152960396f * (vx * vx - vy * vy);

    float t0 = 0.0f, tmax = 1e9f;
    {
        const float o3[3] = { ox, oy, oz };
        const float d3[3] = { dx, dy, dz };
        #pragma unroll
        for (int a = 0; a < 3; a++) {
            if (d3[a] != 0.0f) {
                float inv = 1.0f / d3[a];
                float ta = (-0.5f  - o3[a]) * inv;
                float tb = (127.5f - o3[a]) * inv;
                t0   = fmaxf(t0,   fminf(ta, tb));
                tmax = fminf(tmax, fmaxf(ta, tb));
            }
        }
    }

    float ll = 0.0f;
    float light = 1.0f;
    float aR = 0, aG = 0, aB = 0, aA = 0, aD1 = 0, aD2 = 0;

    int cached_cell = -1;
    float csig[8], cr0[8], cr1[8], cr2[8];

    const int k0 = seg * SPS;
    for (int i = 0; i < SPS; i++) {
        const float t = t0 + (float)(k0 + i) * STEPSZ;
        if (t > tmax) break;

        float px = fminf(fmaxf(ox + t * dx, 0.0f), 127.0f);
        float py = fminf(fmaxf(oy + t * dy, 0.0f), 127.0f);
        float pz = fminf(fmaxf(oz + t * dz, 0.0f), 127.0f);
        const int lx = min(max((int)px, 0), 126);
        const int ly = min(max((int)py, 0), 126);
        const int lz = min(max((int)pz, 0), 126);
        const float fx = px - (float)lx;
        const float fy = py - (float)ly;
        const float fz = pz - (float)lz;

        const int cell = (lx << 14) | (ly << 7) | lz;
        if (cell != cached_cell) {
            cached_cell = cell;
            if (PACKED) {
                #pragma unroll
                for (int c = 0; c < 8; c++) {
                    const int off = (((c >> 2) & 1) << 14) + (((c >> 1) & 1) << 7) + (c & 1);
                    const half8* pr = (const half8*)(pack + (size_t)(cell + off) * 32);
                    const half8 h0 = pr[0], h1 = pr[1], h2 = pr[2], h3 = pr[3];
                    csig[c] = (float)h0[0];
                    cr0[c] = shm[0]*(float)h0[1] + shm[1]*(float)h0[2] + shm[2]*(float)h0[3]
                           + shm[3]*(float)h0[4] + shm[4]*(float)h0[5] + shm[5]*(float)h0[6]
                           + shm[6]*(float)h0[7] + shm[7]*(float)h1[0] + shm[8]*(float)h1[1];
                    cr1[c] = shm[0]*(float)h1[2] + shm[1]*(float)h1[3] + shm[2]*(float)h1[4]
                           + shm[3]*(float)h1[5] + shm[4]*(float)h1[6] + shm[5]*(float)h1[7]
                           + shm[6]*(float)h2[0] + shm[7]*(float)h2[1] + shm[8]*(float)h2[2];
                    cr2[c] = shm[0]*(float)h2[3] + shm[1]*(float)h2[4] + shm[2]*(float)h2[5]
                           + shm[3]*(float)h2[6] + shm[4]*(float)h2[7] + shm[5]*(float)h3[0]
                           + shm[6]*(float)h3[1] + shm[7]*(float)h3[2] + shm[8]*(float)h3[3];
                }
            } else {
                #pragma unroll
                for (int c = 0; c < 8; c++) {
                    const int cdx = (c >> 2) & 1, cdy = (c >> 1) & 1, cdz = c & 1;
                    const int idx = cell + (cdx << 14) + (cdy << 7) + cdz;
                    const int lnk = links[idx];
                    float sg = 0, q0 = 0, q1 = 0, q2 = 0;
                    if (lnk >= 0) {
                        sg = density[lnk];
                        const float* row = sh + (size_t)lnk * 27;
                        #pragma unroll
                        for (int k = 0; k < 9; k++) {
                            const float m = shm[k];
                            q0 += m * row[k];
                            q1 += m * row[9 + k];
                            q2 += m * row[18 + k];
                        }
                    }
                    csig[c] = sg; cr0[c] = q0; cr1[c] = q1; cr2[c] = q2;
                }
            }
        }

        const float gx1 = fx, gx0 = 1.0f - fx;
        const float gy1 = fy, gy0 = 1.0f - fy;
        const float gz1 = fz, gz0 = 1.0f - fz;
        float w[8];
        w[0] = gx0*gy0*gz0; w[1] = gx0*gy0*gz1; w[2] = gx0*gy1*gz0; w[3] = gx0*gy1*gz1;
        w[4] = gx1*gy0*gz0; w[5] = gx1*gy0*gz1; w[6] = gx1*gy1*gz0; w[7] = gx1*gy1*gz1;

        float sigma = 0, c0 = 0, c1 = 0, c2 = 0;
        #pragma unroll
        for (int c = 0; c < 8; c++) {
            sigma += w[c] * csig[c];
            c0    += w[c] * cr0[c];
            c1    += w[c] * cr1[c];
            c2    += w[c] * cr2[c];
        }

        const float la = -STEPSZ * fmaxf(sigma, 0.0f) * ds;
        const float e  = __expf(la);
        const float ws = light * (1.0f - e);
        c0 = fmaxf(c0 + 0.5f, 0.0f);
        c1 = fmaxf(c1 + 0.5f, 0.0f);
        c2 = fmaxf(c2 + 0.5f, 0.0f);

        aR += ws * c0; aG += ws * c1; aB += ws * c2;
        aA += ws;
        const float dd = t * ds;
        aD1 += ws * dd;
        aD2 += ws * dd * dd;
        light *= e;
        ll    += la;
    }

    part[seg][r][0] = aR;  part[seg][r][1] = aG;  part[seg][r][2] = aB;
    part[seg][r][3] = aA;  part[seg][r][4] = aD1; part[seg][r][5] = aD2;
    part[seg][r][6] = ll;
    __syncthreads();

    if (tid < RPB) {
        float pre = 0.0f;
        float R = 0, G = 0, Bc = 0, A = 0, D1 = 0, D2 = 0;
        for (int s = 0; s < SEGS; s++) {
            const float T = __expf(pre);
            R  += T * part[s][tid][0];
            G  += T * part[s][tid][1];
            Bc += T * part[s][tid][2];
            A  += T * part[s][tid][3];
            D1 += T * part[s][tid][4];
            D2 += T * part[s][tid][5];
            pre += part[s][tid][6];
        }
        const float bg    = __expf(pre);
        const float denom = fmaxf(A, 1e-10f);
        const float E     = D1 / denom;
        const float ov    = D2 - 2.0f * E * D1 + E * E * A;

        const int o = (blockIdx.x * RPB + tid) * 6;
        out[o + 0] = R  + bg;
        out[o + 1] = G  + bg;
        out[o + 2] = Bc + bg;
        out[o + 3] = A;
        out[o + 4] = E;
        out[o + 5] = ov / denom;
    }
}

extern "C" void kernel_launch(void* const* d_in, const int* in_sizes, int n_in,
                              void* d_out, int out_size, void* d_ws, size_t ws_size,
                              hipStream_t stream) {
    const float* origins = (const float*)d_in[0];
    const float* dirs    = (const float*)d_in[1];
    const int*   links   = (const int*)d_in[2];
    const float* density = (const float*)d_in[3];
    const float* sh      = (const float*)d_in[4];
    float* out = (float*)d_out;

    dim3 mgrid(NRAYS / RPB);   // 2048 blocks
    dim3 mblock(TPB);          // 256 threads = 8 rays x 32 segments

    if (ws_size >= PACK_BYTES) {
        _Float16* pack = (_Float16*)d_ws;
        repack_kernel<<<dim3(NVOX / 256), dim3(256), 0, stream>>>(links, density, sh, pack);
        march_kernel<true><<<mgrid, mblock, 0, stream>>>(
            origins, dirs, links, density, sh, pack, out);
    } else {
        march_kernel<false><<<mgrid, mblock, 0, stream>>>(
            origins, dirs, links, density, sh, (const _Float16*)nullptr, out);
    }
}

// Round 8
// 453.408 us; speedup vs baseline: 1.9835x; 1.4414x over previous
//
#include <hip/hip_runtime.h>
#include <math.h>

#define GRIDN    128
#define NRAYS    16384
#define STEPSZ   0.5f
#define MAXSTEPS 320
#define SEGS     32
#define SPS      (MAXSTEPS / SEGS)   // 10 steps per segment
#define RPB      8                   // rays per block
#define TPB      (RPB * SEGS)        // 256 threads; wave = 8 rays x 8 segs
#define NVOX     (GRIDN * GRIDN * GRIDN)
// 32-B record per VOXEL: [0:2) f16 density, [2:4) f16 scale, [4:31) 27x int8
// SH quant (sh ~= scale*q), [31] pad. Voxel-indexed; empty voxels = zeros.
#define PACK_BYTES ((size_t)NVOX * 32)

// ---------------------------------------------------------------------------
// Prologue: int8-quantizing repack, r0-proven wave-span structure.
// Wave handles 64 voxels: float4 coalesced span-read of the 64 sh rows into
// LDS (fp32, stride-27 row reads are odd-stride -> conflict-free), per-lane
// rowmax/quantize, 32-B record stores.
// ---------------------------------------------------------------------------
__global__ __launch_bounds__(256, 4)
void repack_kernel(const int*   __restrict__ links,
                   const float* __restrict__ density,
                   const float* __restrict__ sh,
                   unsigned int* __restrict__ pack)
{
    __shared__ float buf[4][64 * 27];   // 27648 B/block
    const int lane  = threadIdx.x & 63;
    const int wv    = threadIdx.x >> 6;
    const int vbase = (blockIdx.x * 4 + wv) * 64;

    // span read: 64 rows = 1728 floats = 432 float4 (16B-aligned: vbase*108)
    float* b = buf[wv];
    const float4* src4 = (const float4*)(sh + (size_t)vbase * 27);
    #pragma unroll
    for (int it = 0; it < 7; it++) {
        const int idx = it * 64 + lane;
        if (idx < 432) {
            const float4 v = src4[idx];
            b[idx * 4 + 0] = v.x; b[idx * 4 + 1] = v.y;
            b[idx * 4 + 2] = v.z; b[idx * 4 + 3] = v.w;
        }
    }

    const int v   = vbase + lane;
    const int lnk = links[v];
    const float dens = (lnk >= 0) ? density[lnk] : 0.0f;
    __syncthreads();

    // gather this voxel's row (every path writes all 27 -> stays in regs)
    float row[27];
    if (lnk >= 0) {
        if (lnk >= vbase && lnk < vbase + 64) {
            const float* r = b + (lnk - vbase) * 27;   // stride-27: conflict-free
            #pragma unroll
            for (int k = 0; k < 27; k++) row[k] = r[k];
        } else {
            const float* r = sh + (size_t)lnk * 27;    // rare general-links gather
            #pragma unroll
            for (int k = 0; k < 27; k++) row[k] = r[k];
        }
    } else {
        #pragma unroll
        for (int k = 0; k < 27; k++) row[k] = 0.0f;
    }

    // quantize: scale = rowmax/127, q = rint(sh/scale) in [-127,127]
    float mx = 0.0f;
    #pragma unroll
    for (int k = 0; k < 27; k++) mx = fmaxf(mx, fabsf(row[k]));
    const float scale = mx * (1.0f / 127.0f);
    const float inv   = (mx > 0.0f) ? (127.0f / mx) : 0.0f;

    unsigned int d[8];
    union { _Float16 h; unsigned short u; } cvt;
    cvt.h = (_Float16)dens;
    const unsigned int dh = cvt.u;
    cvt.h = (_Float16)scale;
    d[0] = dh | ((unsigned int)cvt.u << 16);
    #pragma unroll
    for (int j = 0; j < 7; j++) {
        unsigned int w = 0;
        #pragma unroll
        for (int e = 0; e < 4; e++) {
            const int k = j * 4 + e;
            int q = 0;
            if (k < 27) {
                q = (int)rintf(row[k] * inv);
                q = q > 127 ? 127 : (q < -127 ? -127 : q);
            }
            w |= ((unsigned int)(unsigned char)(signed char)q) << (e * 8);
        }
        d[1 + j] = w;
    }

    uint4* dst = (uint4*)(pack + (size_t)v * 8);
    dst[0] = make_uint4(d[0], d[1], d[2], d[3]);
    dst[1] = make_uint4(d[4], d[5], d[6], d[7]);
}

// ---------------------------------------------------------------------------
// March: r7 structure (8 rays x 32 segs, in-block LDS stitch) with 32-B
// records: 2 x dwordx4 per corner instead of 4 (request count halves — the
// measured wall is gather delivery ∝ requests/bytes). Density f16 (sigma
// numerics identical to r7); SH int8 x per-record f16 scale, scale folded
// into the channel sums.
// ---------------------------------------------------------------------------
#define QB(w, b) ((float)(int)(signed char)(((w) >> ((b) * 8)) & 0xffu))

template <bool PACKED>
__global__ __launch_bounds__(TPB, 6)
void march_kernel(const float* __restrict__ origins,
                  const float* __restrict__ dirs,
                  const int*   __restrict__ links,
                  const float* __restrict__ density,
                  const float* __restrict__ sh,
                  const unsigned int* __restrict__ pack,
                  float* __restrict__ out)
{
    __shared__ float part[SEGS][RPB][8];

    const int tid = threadIdx.x;
    const int r   = tid & (RPB - 1);
    const int seg = tid / RPB;
    const int ray = blockIdx.x * RPB + r;

    // ---- ray setup ----
    const float owx = origins[ray * 3 + 0];
    const float owy = origins[ray * 3 + 1];
    const float owz = origins[ray * 3 + 2];
    const float dwx = dirs[ray * 3 + 0];
    const float dwy = dirs[ray * 3 + 1];
    const float dwz = dirs[ray * 3 + 2];

    const float invn = 1.0f / sqrtf(dwx * dwx + dwy * dwy + dwz * dwz);
    const float vx = dwx * invn, vy = dwy * invn, vz = dwz * invn;

    const float ox = 63.5f + owx * 64.0f;
    const float oy = 63.5f + owy * 64.0f;
    const float oz = 63.5f + owz * 64.0f;

    const float sxx = vx * 64.0f, syy = vy * 64.0f, szz = vz * 64.0f;
    const float ds  = 1.0f / sqrtf(sxx * sxx + syy * syy + szz * szz);
    const float dx = sxx * ds, dy = syy * ds, dz = szz * ds;

    float shm[9];
    shm[0] = 0.28209479177387814f;
    shm[1] = -0.4886025119029199f * vy;
    shm[2] =  0.4886025119029199f * vz;
    shm[3] = -0.4886025119029199f * vx;
    shm[4] =  1.0925484305920792f * vx * vy;
    shm[5] = -1.0925484305920792f * vy * vz;
    shm[6] =  0.31539156525252005f * (2.0f * vz * vz - vx * vx - vy * vy);
    shm[7] = -1.0925484305920792f * vx * vz;
    shm[8] =  0.5462742152960396f * (vx * vx - vy * vy);

    float t0 = 0.0f, tmax = 1e9f;
    {
        const float o3[3] = { ox, oy, oz };
        const float d3[3] = { dx, dy, dz };
        #pragma unroll
        for (int a = 0; a < 3; a++) {
            if (d3[a] != 0.0f) {
                float inv = 1.0f / d3[a];
                float ta = (-0.5f  - o3[a]) * inv;
                float tb = (127.5f - o3[a]) * inv;
                t0   = fmaxf(t0,   fminf(ta, tb));
                tmax = fminf(tmax, fmaxf(ta, tb));
            }
        }
    }

    float ll = 0.0f;
    float light = 1.0f;
    float aR = 0, aG = 0, aB = 0, aA = 0, aD1 = 0, aD2 = 0;

    int cached_cell = -1;
    float csig[8], cr0[8], cr1[8], cr2[8];

    const int k0 = seg * SPS;
    for (int i = 0; i < SPS; i++) {
        const float t = t0 + (float)(k0 + i) * STEPSZ;
        if (t > tmax) break;

        float px = fminf(fmaxf(ox + t * dx, 0.0f), 127.0f);
        float py = fminf(fmaxf(oy + t * dy, 0.0f), 127.0f);
        float pz = fminf(fmaxf(oz + t * dz, 0.0f), 127.0f);
        const int lx = min(max((int)px, 0), 126);
        const int ly = min(max((int)py, 0), 126);
        const int lz = min(max((int)pz, 0), 126);
        const float fx = px - (float)lx;
        const float fy = py - (float)ly;
        const float fz = pz - (float)lz;

        const int cell = (lx << 14) | (ly << 7) | lz;
        if (cell != cached_cell) {
            cached_cell = cell;
            if (PACKED) {
                #pragma unroll
                for (int c = 0; c < 8; c++) {
                    const int off = (((c >> 2) & 1) << 14) + (((c >> 1) & 1) << 7) + (c & 1);
                    const uint4* pr = (const uint4*)(pack + (size_t)(cell + off) * 8);
                    const uint4 A = pr[0], Bq = pr[1];
                    const unsigned int d1 = A.y,  d2 = A.z,  d3 = A.w;
                    const unsigned int d4 = Bq.x, d5 = Bq.y, d6 = Bq.z, d7 = Bq.w;

                    union { unsigned short u; _Float16 h; } cv;
                    cv.u = (unsigned short)(A.x & 0xffffu);
                    csig[c] = (float)cv.h;
                    cv.u = (unsigned short)(A.x >> 16);
                    const float s = (float)cv.h;

                    const float s0 = shm[0]*QB(d1,0) + shm[1]*QB(d1,1) + shm[2]*QB(d1,2)
                                   + shm[3]*QB(d1,3) + shm[4]*QB(d2,0) + shm[5]*QB(d2,1)
                                   + shm[6]*QB(d2,2) + shm[7]*QB(d2,3) + shm[8]*QB(d3,0);
                    const float s1 = shm[0]*QB(d3,1) + shm[1]*QB(d3,2) + shm[2]*QB(d3,3)
                                   + shm[3]*QB(d4,0) + shm[4]*QB(d4,1) + shm[5]*QB(d4,2)
                                   + shm[6]*QB(d4,3) + shm[7]*QB(d5,0) + shm[8]*QB(d5,1);
                    const float s2 = shm[0]*QB(d5,2) + shm[1]*QB(d5,3) + shm[2]*QB(d6,0)
                                   + shm[3]*QB(d6,1) + shm[4]*QB(d6,2) + shm[5]*QB(d6,3)
                                   + shm[6]*QB(d7,0) + shm[7]*QB(d7,1) + shm[8]*QB(d7,2);
                    cr0[c] = s * s0;
                    cr1[c] = s * s1;
                    cr2[c] = s * s2;
                }
            } else {
                #pragma unroll
                for (int c = 0; c < 8; c++) {
                    const int cdx = (c >> 2) & 1, cdy = (c >> 1) & 1, cdz = c & 1;
                    const int idx = cell + (cdx << 14) + (cdy << 7) + cdz;
                    const int lnk = links[idx];
                    float sg = 0, q0 = 0, q1 = 0, q2 = 0;
                    if (lnk >= 0) {
                        sg = density[lnk];
                        const float* row = sh + (size_t)lnk * 27;
                        #pragma unroll
                        for (int k = 0; k < 9; k++) {
                            const float m = shm[k];
                            q0 += m * row[k];
                            q1 += m * row[9 + k];
                            q2 += m * row[18 + k];
                        }
                    }
                    csig[c] = sg; cr0[c] = q0; cr1[c] = q1; cr2[c] = q2;
                }
            }
        }

        const float gx1 = fx, gx0 = 1.0f - fx;
        const float gy1 = fy, gy0 = 1.0f - fy;
        const float gz1 = fz, gz0 = 1.0f - fz;
        float w[8];
        w[0] = gx0*gy0*gz0; w[1] = gx0*gy0*gz1; w[2] = gx0*gy1*gz0; w[3] = gx0*gy1*gz1;
        w[4] = gx1*gy0*gz0; w[5] = gx1*gy0*gz1; w[6] = gx1*gy1*gz0; w[7] = gx1*gy1*gz1;

        float sigma = 0, c0 = 0, c1 = 0, c2 = 0;
        #pragma unroll
        for (int c = 0; c < 8; c++) {
            sigma += w[c] * csig[c];
            c0    += w[c] * cr0[c];
            c1    += w[c] * cr1[c];
            c2    += w[c] * cr2[c];
        }

        const float la = -STEPSZ * fmaxf(sigma, 0.0f) * ds;
        const float e  = __expf(la);
        const float ws = light * (1.0f - e);
        c0 = fmaxf(c0 + 0.5f, 0.0f);
        c1 = fmaxf(c1 + 0.5f, 0.0f);
        c2 = fmaxf(c2 + 0.5f, 0.0f);

        aR += ws * c0; aG += ws * c1; aB += ws * c2;
        aA += ws;
        const float dd = t * ds;
        aD1 += ws * dd;
        aD2 += ws * dd * dd;
        light *= e;
        ll    += la;
    }

    part[seg][r][0] = aR;  part[seg][r][1] = aG;  part[seg][r][2] = aB;
    part[seg][r][3] = aA;  part[seg][r][4] = aD1; part[seg][r][5] = aD2;
    part[seg][r][6] = ll;
    __syncthreads();

    if (tid < RPB) {
        float pre = 0.0f;
        float R = 0, G = 0, Bc = 0, A = 0, D1 = 0, D2 = 0;
        for (int s = 0; s < SEGS; s++) {
            const float T = __expf(pre);
            R  += T * part[s][tid][0];
            G  += T * part[s][tid][1];
            Bc += T * part[s][tid][2];
            A  += T * part[s][tid][3];
            D1 += T * part[s][tid][4];
            D2 += T * part[s][tid][5];
            pre += part[s][tid][6];
        }
        const float bg    = __expf(pre);
        const float denom = fmaxf(A, 1e-10f);
        const float E     = D1 / denom;
        const float ov    = D2 - 2.0f * E * D1 + E * E * A;

        const int o = (blockIdx.x * RPB + tid) * 6;
        out[o + 0] = R  + bg;
        out[o + 1] = G  + bg;
        out[o + 2] = Bc + bg;
        out[o + 3] = A;
        out[o + 4] = E;
        out[o + 5] = ov / denom;
    }
}

extern "C" void kernel_launch(void* const* d_in, const int* in_sizes, int n_in,
                              void* d_out, int out_size, void* d_ws, size_t ws_size,
                              hipStream_t stream) {
    const float* origins = (const float*)d_in[0];
    const float* dirs    = (const float*)d_in[1];
    const int*   links   = (const int*)d_in[2];
    const float* density = (const float*)d_in[3];
    const float* sh      = (const float*)d_in[4];
    float* out = (float*)d_out;

    dim3 mgrid(NRAYS / RPB);   // 2048 blocks
    dim3 mblock(TPB);          // 256 threads = 8 rays x 32 segments

    if (ws_size >= PACK_BYTES) {
        unsigned int* pack = (unsigned int*)d_ws;
        repack_kernel<<<dim3(NVOX / 256), dim3(256), 0, stream>>>(links, density, sh, pack);
        march_kernel<true><<<mgrid, mblock, 0, stream>>>(
            origins, dirs, links, density, sh, pack, out);
    } else {
        march_kernel<false><<<mgrid, mblock, 0, stream>>>(
            origins, dirs, links, density, sh, (const unsigned int*)nullptr, out);
    }
}